// Round 4
// baseline (178.204 us; speedup 1.0000x reference)
//
#include <hip/hip_runtime.h>
#include <hip/hip_bf16.h>
#include <stdint.h>

#define N_TOT   16384
#define N_LB    2048
#define C_DIM   100

typedef __attribute__((ext_vector_type(8))) short s16x8;
typedef __attribute__((ext_vector_type(4))) float f32x4;

#if __has_builtin(__builtin_amdgcn_exp2f)
#define EXP2F __builtin_amdgcn_exp2f
#else
#define EXP2F exp2f
#endif

__device__ __forceinline__ short f2bf(float x) {
  union { float f; unsigned u; } v; v.f = x;
  unsigned r = (v.u + 0x7fffu + ((v.u >> 16) & 1u)) >> 16;
  return (short)r;
}
__device__ __forceinline__ float bf2f(short h) {
  union { unsigned u; float f; } v; v.u = ((unsigned)(unsigned short)h) << 16; return v.f;
}
__device__ __forceinline__ int slotsw(int c, int q) {
  return (c ^ q ^ ((q & 8) >> 1)) & 15;
}
__device__ __forceinline__ unsigned cvtpk_bf16(float a, float b) {
  unsigned r;
  asm("v_cvt_pk_bf16_f32 %0, %1, %2" : "=v"(r) : "v"(a), "v"(b));
  return r;
}

// ---------------- Kernel P: fused prep (normalize + classval + passthrough copies) ----
__global__ __launch_bounds__(256) void k_prep(const float* __restrict__ anc,
                                              const float* __restrict__ pos,
                                              const float* __restrict__ lbf,
                                              const float* __restrict__ onehot,
                                              const float* __restrict__ lg1,
                                              const float* __restrict__ lg2,
                                              short* __restrict__ feats_ws,
                                              short* __restrict__ v_ws,
                                              float* __restrict__ out) {
  const int bid = blockIdx.x, tid = threadIdx.x;
  const int wid = tid >> 6, lane = tid & 63;
  if (bid < 4096) {
    const int r = bid * 4 + wid;
    const float* src = (r < N_LB) ? (lbf + (size_t)r * 128)
                     : ((r < 9216) ? (anc + (size_t)(r - 2048) * 128)
                                   : (pos + (size_t)(r - 9216) * 128));
    float2 x = *(const float2*)(src + lane * 2);
    float ss = x.x * x.x + x.y * x.y;
    #pragma unroll
    for (int o = 32; o; o >>= 1) ss += __shfl_xor(ss, o);
    float scale = rsqrtf(fmaxf(ss, 1e-24f));
    const int kt = r >> 4, q = r & 15;
    union { short s[2]; unsigned u; } w;
    w.s[0] = f2bf(x.x * scale);
    w.s[1] = f2bf(x.y * scale);
    *(unsigned*)(feats_ws + (size_t)kt * 2048 + q * 128 +
                 (slotsw(lane >> 2, q) << 3) + ((lane & 3) << 1)) = w.u;
  } else if (bid < 8192) {
    const int r = (bid - 4096) * 4 + wid;
    const int c0 = lane, c1 = lane + 64;
    float v0, v1;
    if (r < N_LB) {
      v0 = (c0 < C_DIM) ? onehot[(size_t)r * C_DIM + c0] : 0.f;
      v1 = (c1 < C_DIM) ? onehot[(size_t)r * C_DIM + c1] : 0.f;
    } else {
      const float* lr = (r < 9216) ? (lg1 + (size_t)(r - 2048) * C_DIM)
                                   : (lg2 + (size_t)(r - 9216) * C_DIM);
      float x0 = (c0 < C_DIM) ? lr[c0] : -3e38f;
      float x1 = (c1 < C_DIM) ? lr[c1] : -3e38f;
      float m = fmaxf(x0, x1);
      #pragma unroll
      for (int o = 32; o; o >>= 1) m = fmaxf(m, __shfl_xor(m, o));
      float e0 = (c0 < C_DIM) ? EXP2F((x0 - m) * 1.44269504f) : 0.f;
      float e1 = (c1 < C_DIM) ? EXP2F((x1 - m) * 1.44269504f) : 0.f;
      float s = e0 + e1;
      #pragma unroll
      for (int o = 32; o; o >>= 1) s += __shfl_xor(s, o);
      float inv = 1.0f / s;
      v0 = e0 * inv;
      v1 = e1 * inv;
    }
    const int T = r >> 5, rr = r & 31;
    const int jj = (((rr >> 4) & 1) << 2) | (rr & 3);
    const int gg = (rr & 15) >> 2;
    {
      const int ch = c0 >> 4, qq = c0 & 15;
      v_ws[(size_t)T * 4096 + ch * 512 + gg * 128 + ((qq ^ (gg << 2)) << 3) + jj] = f2bf(v0);
    }
    {
      const int ch = c1 >> 4, qq = c1 & 15;
      v_ws[(size_t)T * 4096 + ch * 512 + gg * 128 + ((qq ^ (gg << 2)) << 3) + jj] = f2bf(v1);
    }
  } else {
    const long long i4 = (long long)(bid - 8192) * 256 + tid;
    const long long f = i4 * 4;
    float4 v;
    if (f < 917504)        v = *(const float4*)(anc + f);
    else if (f < 1835008)  v = *(const float4*)(pos + (f - 917504));
    else if (f < 2097152)  v = *(const float4*)(lbf + (f - 1835008));
    else                   v = *(const float4*)(onehot + (f - 2097152));
    *(float4*)(out + f) = v;
  }
}

// ---------------- Kernel C: attention ----------------
__device__ __forceinline__ void stage64(const short* kg, short* dst, int wave, int lane) {
  #pragma unroll
  for (int i = 0; i < 4; ++i) {
    const int blk = wave * 4 + i;  // 16 chunks of 1KB per 16KB tile (64 rows)
    __builtin_amdgcn_global_load_lds(
        (const __attribute__((address_space(1))) void*)(kg + blk * 512 + lane * 8),
        (__attribute__((address_space(3))) void*)(dst + blk * 512), 16, 0, 0);
  }
}

__global__ __launch_bounds__(256, 3) void k_attn(const short* __restrict__ feats,
                                                 const short* __restrict__ vws,
                                                 short* __restrict__ pO,
                                                 float* __restrict__ pL,
                                                 float* __restrict__ outp,
                                                 int S, int nt2) {
  __shared__ __align__(16) short lk[2][8192];  // two 64-row K buffers (16KB each)
  const int tid = threadIdx.x;
  const int wave = tid >> 6, lane = tid & 63;
  const int q = lane & 15, g = lane >> 4;
  const int bid = blockIdx.x;
  const int slice = bid % S;            // consecutive bids round-robin XCDs: slice==XCD
  const int qsup = (bid / S) * 4 + wave;
  const int t0h = slice * nt2;          // 64-row tile units

  s16x8 bQ[2][4];
  #pragma unroll
  for (int set = 0; set < 2; ++set)
    #pragma unroll
    for (int kk = 0; kk < 4; ++kk)
      bQ[set][kk] = *(const s16x8*)(feats + (size_t)(qsup * 2 + set) * 2048 + q * 128 +
                                    (slotsw((kk << 2) | g, q) << 3));

  f32x4 zero = {0.f, 0.f, 0.f, 0.f};
  f32x4 oacc[2][7];
  #pragma unroll
  for (int set = 0; set < 2; ++set)
    #pragma unroll
    for (int c = 0; c < 7; ++c) oacc[set][c] = zero;
  float lsum[2] = {0.f, 0.f};

  int dso[4];
  #pragma unroll
  for (int kk = 0; kk < 4; ++kk) dso[kk] = q * 128 + (slotsw((kk << 2) | g, q) << 3);
  const int vfo = g * 128 + ((q ^ (g << 2)) << 3);

  stage64(feats + (size_t)t0h * 8192, lk[0], wave, lane);
  __syncthreads();

  for (int t = 0; t < nt2; ++t) {
    const int cur = t & 1;
    if (t + 1 < nt2)
      stage64(feats + (size_t)(t0h + t + 1) * 8192, lk[cur ^ 1], wave, lane);
    const short* lkc = lk[cur];
    const short* vb = vws + (size_t)(t0h + t) * 8192 + vfo;

    #pragma unroll
    for (int sub = 0; sub < 2; ++sub) {
      const short* lks = lkc + sub * 4096;
      // K fragments for 32 K-rows
      s16x8 aK0[4], aK1[4];
      #pragma unroll
      for (int kk = 0; kk < 4; ++kk) {
        aK0[kk] = *(const s16x8*)(lks + dso[kk]);
        aK1[kk] = *(const s16x8*)(lks + 2048 + dso[kk]);
      }
      // V fragments straight from global (L1/L2-resident)
      s16x8 bV[7];
      #pragma unroll
      for (int c = 0; c < 7; ++c) bV[c] = *(const s16x8*)(vb + sub * 4096 + c * 512);

      // swapped QK^T
      f32x4 s0[2] = {zero, zero}, s1[2] = {zero, zero};
      __builtin_amdgcn_s_setprio(1);
      #pragma unroll
      for (int kk = 0; kk < 4; ++kk)
        #pragma unroll
        for (int set = 0; set < 2; ++set) {
          s0[set] = __builtin_amdgcn_mfma_f32_16x16x32_bf16(aK0[kk], bQ[set][kk], s0[set], 0, 0, 0);
          s1[set] = __builtin_amdgcn_mfma_f32_16x16x32_bf16(aK1[kk], bQ[set][kk], s1[set], 0, 0, 0);
        }
      __builtin_amdgcn_s_setprio(0);

      // p = exp(10 s - 10); pack to bf16 A-frags
      s16x8 pf[2];
      #pragma unroll
      for (int set = 0; set < 2; ++set) {
        float p[8];
        #pragma unroll
        for (int r = 0; r < 4; ++r) {
          p[r]     = EXP2F(s0[set][r] * 14.4269504f - 14.4269504f);
          p[r + 4] = EXP2F(s1[set][r] * 14.4269504f - 14.4269504f);
        }
        lsum[set] += ((p[0] + p[1]) + (p[2] + p[3])) + ((p[4] + p[5]) + (p[6] + p[7]));
        union { unsigned w[4]; s16x8 h; } pu;
        pu.w[0] = cvtpk_bf16(p[0], p[1]);
        pu.w[1] = cvtpk_bf16(p[2], p[3]);
        pu.w[2] = cvtpk_bf16(p[4], p[5]);
        pu.w[3] = cvtpk_bf16(p[6], p[7]);
        pf[set] = pu.h;
      }

      // PV
      __builtin_amdgcn_s_setprio(1);
      #pragma unroll
      for (int c = 0; c < 7; ++c)
        #pragma unroll
        for (int set = 0; set < 2; ++set)
          oacc[set][c] = __builtin_amdgcn_mfma_f32_16x16x32_bf16(pf[set], bV[c], oacc[set][c], 0, 0, 0);
      __builtin_amdgcn_s_setprio(0);
    }
    __syncthreads();
  }

  // epilogue: reduce lsum over lane groups, then write
  #pragma unroll
  for (int set = 0; set < 2; ++set) {
    float ls = lsum[set];
    ls += __shfl_xor(ls, 16);
    ls += __shfl_xor(ls, 32);
    const int row0 = qsup * 32 + set * 16;
    if (S == 1) {
      float linv[4];
      #pragma unroll
      for (int r = 0; r < 4; ++r) linv[r] = 1.0f / __shfl(ls, (g << 2) | r);
      #pragma unroll
      for (int c = 0; c < 7; ++c) {
        const int col = c * 16 + q;
        if (col < C_DIM)
          #pragma unroll
          for (int r = 0; r < 4; ++r)
            outp[(size_t)(row0 + (g << 2) + r) * C_DIM + col] = oacc[set][c][r] * linv[r];
      }
    } else {
      if (lane < 16) pL[(size_t)slice * N_TOT + row0 + lane] = ls;
      #pragma unroll
      for (int c = 0; c < 7; ++c)
        #pragma unroll
        for (int r = 0; r < 4; ++r)
          pO[((size_t)slice * N_TOT + row0 + (g << 2) + r) * 112 + c * 16 + q] =
              f2bf(oacc[set][c][r]);
    }
  }
}

// ---------------- Kernel D: combine K-split partials ----------------
__global__ void k_combine(const short* __restrict__ pO, const float* __restrict__ pL,
                          float* __restrict__ out, int S) {
  const int row = blockIdx.x * 2 + (threadIdx.x >> 7);
  const int c = threadIdx.x & 127;
  float l = 0.f, o = 0.f;
  for (int s = 0; s < S; ++s) {
    l += pL[(size_t)s * N_TOT + row];
    if (c < 112) o += bf2f(pO[((size_t)s * N_TOT + row) * 112 + c]);
  }
  if (c < C_DIM) out[(size_t)row * C_DIM + c] = o / l;
}

extern "C" void kernel_launch(void* const* d_in, const int* in_sizes, int n_in,
                              void* d_out, int out_size, void* d_ws, size_t ws_size,
                              hipStream_t stream) {
  const float* anchor   = (const float*)d_in[0];  // 7168x128
  const float* positive = (const float*)d_in[1];  // 7168x128
  const float* lb_feat  = (const float*)d_in[2];  // 2048x128
  const float* lb_onehot= (const float*)d_in[3];  // 2048x100
  const float* lg1      = (const float*)d_in[5];  // 7168x100
  const float* lg2      = (const float*)d_in[6];  // 7168x100
  float* out = (float*)d_out;

  short* feats_ws = (short*)d_ws;              // 4 MB
  short* v_ws     = feats_ws + 2097152;        // 4 MB
  float* pL       = (float*)(v_ws + 2097152);  // 512 KB (8 slices max)
  short* pO       = (short*)(pL + 8 * N_TOT);  // S * 16384 * 112 * 2B

  int S = 8;
  while (S > 1 && 8912896ull + (size_t)S * N_TOT * 112 * 2 > ws_size) S >>= 1;
  const int nt2 = (512 / S) >> 1;

  k_prep<<<10440, 256, 0, stream>>>(anchor, positive, lb_feat, lb_onehot, lg1, lg2,
                                    feats_ws, v_ws, out);

  float* attn_out = out + 2301952;
  k_attn<<<128 * S, 256, 0, stream>>>(feats_ws, v_ws, pO, pL, attn_out, S, nt2);
  if (S > 1)
    k_combine<<<N_TOT / 2, 256, 0, stream>>>(pO, pL, attn_out, S);
}

// Round 5
// 142.978 us; speedup vs baseline: 1.2464x; 1.2464x over previous
//
#include <hip/hip_runtime.h>
#include <hip/hip_bf16.h>
#include <stdint.h>

#define N_TOT   16384
#define N_LB    2048
#define C_DIM   100

typedef __attribute__((ext_vector_type(8))) short s16x8;
typedef __attribute__((ext_vector_type(4))) float f32x4;

#if __has_builtin(__builtin_amdgcn_exp2f)
#define EXP2F __builtin_amdgcn_exp2f
#else
#define EXP2F exp2f
#endif

__device__ __forceinline__ short f2bf(float x) {
  union { float f; unsigned u; } v; v.f = x;
  unsigned r = (v.u + 0x7fffu + ((v.u >> 16) & 1u)) >> 16;
  return (short)r;
}
__device__ __forceinline__ float bf2f(short h) {
  union { unsigned u; float f; } v; v.u = ((unsigned)(unsigned short)h) << 16; return v.f;
}
__device__ __forceinline__ int slotsw(int c, int q) {
  return (c ^ q ^ ((q & 8) >> 1)) & 15;
}
__device__ __forceinline__ unsigned cvtpk_bf16(float a, float b) {
  unsigned r;
  asm("v_cvt_pk_bf16_f32 %0, %1, %2" : "=v"(r) : "v"(a), "v"(b));
  return r;
}

// ---------------- Kernel P: fused prep (normalize + classval + copies) ----------------
// Writes feats_ws (K side, unit-normalized) AND feats_q (Q side, pre-scaled by
// 10*log2(e) = 14.4269504 so attention computes p = exp2(qk') with no VALU pre-op).
__global__ __launch_bounds__(256) void k_prep(const float* __restrict__ anc,
                                              const float* __restrict__ pos,
                                              const float* __restrict__ lbf,
                                              const float* __restrict__ onehot,
                                              const float* __restrict__ lg1,
                                              const float* __restrict__ lg2,
                                              short* __restrict__ feats_ws,
                                              short* __restrict__ feats_q,
                                              short* __restrict__ v_ws,
                                              float* __restrict__ out) {
  const int bid = blockIdx.x, tid = threadIdx.x;
  const int wid = tid >> 6, lane = tid & 63;
  if (bid < 4096) {
    const int r = bid * 4 + wid;
    const float* src = (r < N_LB) ? (lbf + (size_t)r * 128)
                     : ((r < 9216) ? (anc + (size_t)(r - 2048) * 128)
                                   : (pos + (size_t)(r - 9216) * 128));
    float2 x = *(const float2*)(src + lane * 2);
    float ss = x.x * x.x + x.y * x.y;
    #pragma unroll
    for (int o = 32; o; o >>= 1) ss += __shfl_xor(ss, o);
    float scale = rsqrtf(fmaxf(ss, 1e-24f));
    float scq = scale * 14.4269504f;
    const int kt = r >> 4, q = r & 15;
    const size_t idx = (size_t)kt * 2048 + q * 128 + (slotsw(lane >> 2, q) << 3) + ((lane & 3) << 1);
    union { short s[2]; unsigned u; } w;
    w.s[0] = f2bf(x.x * scale);  w.s[1] = f2bf(x.y * scale);
    *(unsigned*)(feats_ws + idx) = w.u;
    w.s[0] = f2bf(x.x * scq);    w.s[1] = f2bf(x.y * scq);
    *(unsigned*)(feats_q + idx) = w.u;
  } else if (bid < 8192) {
    const int r = (bid - 4096) * 4 + wid;
    const int c0 = lane, c1 = lane + 64;
    float v0, v1;
    if (r < N_LB) {
      v0 = (c0 < C_DIM) ? onehot[(size_t)r * C_DIM + c0] : 0.f;
      v1 = (c1 < C_DIM) ? onehot[(size_t)r * C_DIM + c1] : 0.f;
    } else {
      const float* lr = (r < 9216) ? (lg1 + (size_t)(r - 2048) * C_DIM)
                                   : (lg2 + (size_t)(r - 9216) * C_DIM);
      float x0 = (c0 < C_DIM) ? lr[c0] : -3e38f;
      float x1 = (c1 < C_DIM) ? lr[c1] : -3e38f;
      float m = fmaxf(x0, x1);
      #pragma unroll
      for (int o = 32; o; o >>= 1) m = fmaxf(m, __shfl_xor(m, o));
      float e0 = (c0 < C_DIM) ? EXP2F((x0 - m) * 1.44269504f) : 0.f;
      float e1 = (c1 < C_DIM) ? EXP2F((x1 - m) * 1.44269504f) : 0.f;
      float s = e0 + e1;
      #pragma unroll
      for (int o = 32; o; o >>= 1) s += __shfl_xor(s, o);
      float inv = 1.0f / s;
      v0 = e0 * inv;
      v1 = e1 * inv;
    }
    const int T = r >> 5, rr = r & 31;
    const int jj = (((rr >> 4) & 1) << 2) | (rr & 3);
    const int gg = (rr & 15) >> 2;
    {
      const int ch = c0 >> 4, qq = c0 & 15;
      v_ws[(size_t)T * 4096 + ch * 512 + gg * 128 + ((qq ^ (gg << 2)) << 3) + jj] = f2bf(v0);
    }
    {
      const int ch = c1 >> 4, qq = c1 & 15;
      v_ws[(size_t)T * 4096 + ch * 512 + gg * 128 + ((qq ^ (gg << 2)) << 3) + jj] = f2bf(v1);
    }
  } else {
    const long long i4 = (long long)(bid - 8192) * 256 + tid;
    const long long f = i4 * 4;
    float4 v;
    if (f < 917504)        v = *(const float4*)(anc + f);
    else if (f < 1835008)  v = *(const float4*)(pos + (f - 917504));
    else if (f < 2097152)  v = *(const float4*)(lbf + (f - 1835008));
    else                   v = *(const float4*)(onehot + (f - 2097152));
    *(float4*)(out + f) = v;
  }
}

// ---------------- Kernel C: attention ----------------
__device__ __forceinline__ void stage64(const short* kg, short* dst, int wave, int lane) {
  #pragma unroll
  for (int i = 0; i < 4; ++i) {
    const int blk = wave * 4 + i;  // 16 chunks of 1KB per 16KB tile (64 rows)
    __builtin_amdgcn_global_load_lds(
        (const __attribute__((address_space(1))) void*)(kg + blk * 512 + lane * 8),
        (__attribute__((address_space(3))) void*)(dst + blk * 512), 16, 0, 0);
  }
}

__global__ __launch_bounds__(256, 2) void k_attn(const short* __restrict__ feats,
                                                 const short* __restrict__ qfeats,
                                                 const short* __restrict__ vws,
                                                 short* __restrict__ pO,
                                                 float* __restrict__ pL,
                                                 float* __restrict__ outp,
                                                 int S, int nt2) {
  __shared__ __align__(16) short lk[2][8192];  // two 64-row K buffers (16KB each)
  const int tid = threadIdx.x;
  const int wave = tid >> 6, lane = tid & 63;
  const int q = lane & 15, g = lane >> 4;
  const int bid = blockIdx.x;
  const int slice = bid % S;            // consecutive bids round-robin XCDs: slice==XCD
  const int qsup = (bid / S) * 4 + wave;
  const int t0h = slice * nt2;          // 64-row tile units

  // prologue vmem: 8 bQ loads + 4 stage gl_lds = 12 ops, all retired by the
  // iter-0 vmcnt(14) (26 outstanding -> 14 keeps exactly the 14 V loads).
  s16x8 bQ[2][4];
  #pragma unroll
  for (int set = 0; set < 2; ++set)
    #pragma unroll
    for (int kk = 0; kk < 4; ++kk)
      bQ[set][kk] = *(const s16x8*)(qfeats + (size_t)(qsup * 2 + set) * 2048 + q * 128 +
                                    (slotsw((kk << 2) | g, q) << 3));

  f32x4 zero = {0.f, 0.f, 0.f, 0.f};
  f32x4 oacc[2][7];
  #pragma unroll
  for (int set = 0; set < 2; ++set)
    #pragma unroll
    for (int c = 0; c < 7; ++c) oacc[set][c] = zero;
  float lsum[2] = {0.f, 0.f};

  int dso[4];
  #pragma unroll
  for (int kk = 0; kk < 4; ++kk) dso[kk] = q * 128 + (slotsw((kk << 2) | g, q) << 3);
  const int vfo = g * 128 + ((q ^ (g << 2)) << 3);

  stage64(feats + (size_t)t0h * 8192, lk[0], wave, lane);
  __builtin_amdgcn_sched_barrier(0);   // pin prologue vmem above the loop

  for (int t = 0; t < nt2; ++t) {
    const int cur = t & 1;
    // ---- (1) V loads for this tile: exactly 14 dwordx4, issued first ----
    const short* vb = vws + (size_t)(t0h + t) * 8192 + vfo;
    s16x8 bV[14];
    #pragma unroll
    for (int sub = 0; sub < 2; ++sub)
      #pragma unroll
      for (int c = 0; c < 7; ++c)
        bV[sub * 7 + c] = *(const s16x8*)(vb + sub * 4096 + c * 512);

    // ---- (2) counted wait: retire stage(t) (queue = [stage:4][V:14]) ----
    asm volatile("s_waitcnt vmcnt(14)" ::: "memory");
    __builtin_amdgcn_s_barrier();       // all waves' stage(t) visible in LDS
    __builtin_amdgcn_sched_barrier(0);

    // ---- (3) prefetch stage(t+1) into the other buffer (stays in flight) ----
    stage64(feats + (size_t)(t0h + t + 1) * 8192, lk[cur ^ 1], wave, lane);

    const short* lkc = lk[cur];
    #pragma unroll
    for (int sub = 0; sub < 2; ++sub) {
      const short* lks = lkc + sub * 4096;
      s16x8 aK0[4], aK1[4];
      #pragma unroll
      for (int kk = 0; kk < 4; ++kk) {
        aK0[kk] = *(const s16x8*)(lks + dso[kk]);
        aK1[kk] = *(const s16x8*)(lks + 2048 + dso[kk]);
      }
      // swapped QK^T (Q pre-scaled: s' = 14.43 * q.k)
      f32x4 s0[2] = {zero, zero}, s1[2] = {zero, zero};
      __builtin_amdgcn_s_setprio(1);
      #pragma unroll
      for (int kk = 0; kk < 4; ++kk)
        #pragma unroll
        for (int set = 0; set < 2; ++set) {
          s0[set] = __builtin_amdgcn_mfma_f32_16x16x32_bf16(aK0[kk], bQ[set][kk], s0[set], 0, 0, 0);
          s1[set] = __builtin_amdgcn_mfma_f32_16x16x32_bf16(aK1[kk], bQ[set][kk], s1[set], 0, 0, 0);
        }
      __builtin_amdgcn_s_setprio(0);

      // p = exp2(s') — unnormalized (2^14.43 scale cancels in O/l)
      s16x8 pf[2];
      #pragma unroll
      for (int set = 0; set < 2; ++set) {
        float p[8];
        #pragma unroll
        for (int r = 0; r < 4; ++r) {
          p[r]     = EXP2F(s0[set][r]);
          p[r + 4] = EXP2F(s1[set][r]);
        }
        lsum[set] += ((p[0] + p[1]) + (p[2] + p[3])) + ((p[4] + p[5]) + (p[6] + p[7]));
        union { unsigned w[4]; s16x8 h; } pu;
        pu.w[0] = cvtpk_bf16(p[0], p[1]);
        pu.w[1] = cvtpk_bf16(p[2], p[3]);
        pu.w[2] = cvtpk_bf16(p[4], p[5]);
        pu.w[3] = cvtpk_bf16(p[6], p[7]);
        pf[set] = pu.h;
      }

      // PV (compiler emits counted vmcnt for bV; stage(t+1) stays in flight)
      __builtin_amdgcn_s_setprio(1);
      #pragma unroll
      for (int c = 0; c < 7; ++c)
        #pragma unroll
        for (int set = 0; set < 2; ++set)
          oacc[set][c] = __builtin_amdgcn_mfma_f32_16x16x32_bf16(pf[set], bV[sub * 7 + c], oacc[set][c], 0, 0, 0);
      __builtin_amdgcn_s_setprio(0);
    }
  }

  // epilogue (no barrier needed; lsum reduced via shuffles)
  #pragma unroll
  for (int set = 0; set < 2; ++set) {
    float ls = lsum[set];
    ls += __shfl_xor(ls, 16);
    ls += __shfl_xor(ls, 32);
    const int row0 = qsup * 32 + set * 16;
    if (S == 1) {
      float linv[4];
      #pragma unroll
      for (int r = 0; r < 4; ++r) linv[r] = 1.0f / __shfl(ls, (g << 2) | r);
      #pragma unroll
      for (int c = 0; c < 7; ++c) {
        const int col = c * 16 + q;
        if (col < C_DIM)
          #pragma unroll
          for (int r = 0; r < 4; ++r)
            outp[(size_t)(row0 + (g << 2) + r) * C_DIM + col] = oacc[set][c][r] * linv[r];
      }
    } else {
      if (lane < 16) pL[(size_t)slice * N_TOT + row0 + lane] = ls;
      #pragma unroll
      for (int c = 0; c < 7; ++c)
        #pragma unroll
        for (int r = 0; r < 4; ++r)
          pO[((size_t)slice * N_TOT + row0 + (g << 2) + r) * 112 + c * 16 + q] =
              f2bf(oacc[set][c][r]);
    }
  }
}

// ---------------- Kernel D: combine K-split partials ----------------
__global__ void k_combine(const short* __restrict__ pO, const float* __restrict__ pL,
                          float* __restrict__ out, int S) {
  const int row = blockIdx.x * 2 + (threadIdx.x >> 7);
  const int c = threadIdx.x & 127;
  float l = 0.f, o = 0.f;
  for (int s = 0; s < S; ++s) {
    l += pL[(size_t)s * N_TOT + row];
    if (c < 112) o += bf2f(pO[((size_t)s * N_TOT + row) * 112 + c]);
  }
  if (c < C_DIM) out[(size_t)row * C_DIM + c] = o / l;
}

extern "C" void kernel_launch(void* const* d_in, const int* in_sizes, int n_in,
                              void* d_out, int out_size, void* d_ws, size_t ws_size,
                              hipStream_t stream) {
  const float* anchor   = (const float*)d_in[0];  // 7168x128
  const float* positive = (const float*)d_in[1];  // 7168x128
  const float* lb_feat  = (const float*)d_in[2];  // 2048x128
  const float* lb_onehot= (const float*)d_in[3];  // 2048x100
  const float* lg1      = (const float*)d_in[5];  // 7168x100
  const float* lg2      = (const float*)d_in[6];  // 7168x100
  float* out = (float*)d_out;

  short* feats_ws = (short*)d_ws;              // 4 MB (K side)
  short* feats_q  = feats_ws + 2097152;        // 4 MB (Q side, pre-scaled)
  short* v_ws     = feats_q + 2097152;         // 4 MB
  float* pL       = (float*)(v_ws + 2097152);  // 512 KB (8 slices max)
  short* pO       = (short*)(pL + 8 * N_TOT);  // S * 16384 * 112 * 2B

  int S = 8;
  while (S > 1 && 13107200ull + (size_t)S * N_TOT * 112 * 2 > ws_size) S >>= 1;
  const int nt2 = (512 / S) >> 1;

  k_prep<<<10440, 256, 0, stream>>>(anchor, positive, lb_feat, lb_onehot, lg1, lg2,
                                    feats_ws, feats_q, v_ws, out);

  float* attn_out = out + 2301952;
  k_attn<<<128 * S, 256, 0, stream>>>(feats_ws, feats_q, v_ws, pO, pL, attn_out, S, nt2);
  if (S > 1)
    k_combine<<<N_TOT / 2, 256, 0, stream>>>(pO, pL, attn_out, S);
}

// Round 7
// 128.519 us; speedup vs baseline: 1.3866x; 1.1125x over previous
//
#include <hip/hip_runtime.h>
#include <hip/hip_bf16.h>
#include <stdint.h>

#define N_TOT   16384
#define N_LB    2048
#define C_DIM   100

typedef __attribute__((ext_vector_type(8))) short s16x8;
typedef __attribute__((ext_vector_type(4))) float f32x4;
typedef __attribute__((ext_vector_type(4))) int   i32x4;

#if __has_builtin(__builtin_amdgcn_exp2f)
#define EXP2F __builtin_amdgcn_exp2f
#else
#define EXP2F exp2f
#endif

// score scale: 10*log2(e) / 127^2  (int8 dot -> log2-domain score)
#define SCONV 8.94477e-4f

__device__ __forceinline__ short f2bf(float x) {
  union { float f; unsigned u; } v; v.f = x;
  unsigned r = (v.u + 0x7fffu + ((v.u >> 16) & 1u)) >> 16;
  return (short)r;
}
__device__ __forceinline__ float bf2f(short h) {
  union { unsigned u; float f; } v; v.u = ((unsigned)(unsigned short)h) << 16; return v.f;
}
__device__ __forceinline__ unsigned cvtpk_bf16(float a, float b) {
  unsigned r;
  asm("v_cvt_pk_bf16_f32 %0, %1, %2" : "=v"(r) : "v"(a), "v"(b));
  return r;
}
// 16-byte-slot swizzle within a 128B row: slot' = (s ^ q ^ (q>>3)) & 7
// -> the 16 lanes of a row-group hit 8 slots 2x each = 2-way (free) on LDS banks
__device__ __forceinline__ int sw3(int s, int q) {
  return (s ^ q ^ (q >> 3)) & 7;
}

// ---------------- Kernel P: fused prep (normalize->int8 + classval + copies) ----------------
__global__ __launch_bounds__(256) void k_prep(const float* __restrict__ anc,
                                              const float* __restrict__ pos,
                                              const float* __restrict__ lbf,
                                              const float* __restrict__ onehot,
                                              const float* __restrict__ lg1,
                                              const float* __restrict__ lg2,
                                              signed char* __restrict__ ks8,
                                              short* __restrict__ v_ws,
                                              float* __restrict__ out) {
  const int bid = blockIdx.x, tid = threadIdx.x;
  const int wid = tid >> 6, lane = tid & 63;
  if (bid < 4096) {
    // l2-normalize -> int8 (x127), byte-slot-swizzled row-major [16384][128]
    const int r = bid * 4 + wid;
    const float* src = (r < N_LB) ? (lbf + (size_t)r * 128)
                     : ((r < 9216) ? (anc + (size_t)(r - 2048) * 128)
                                   : (pos + (size_t)(r - 9216) * 128));
    float2 x = *(const float2*)(src + lane * 2);
    float ss = x.x * x.x + x.y * x.y;
    #pragma unroll
    for (int o = 32; o; o >>= 1) ss += __shfl_xor(ss, o);
    float s127 = rsqrtf(fmaxf(ss, 1e-24f)) * 127.0f;
    int a = __float2int_rn(x.x * s127);
    int b = __float2int_rn(x.y * s127);
    a = max(-127, min(127, a));
    b = max(-127, min(127, b));
    const int q = r & 15;
    const int slot = sw3(lane >> 3, q);
    *(unsigned short*)(ks8 + (size_t)r * 128 + slot * 16 + ((lane * 2) & 15)) =
        (unsigned short)((a & 0xff) | ((b & 0xff) << 8));
  } else if (bid < 8192) {
    // class_val rows -> bf16, PV B-frag order (unchanged, verified R1-R5)
    const int r = (bid - 4096) * 4 + wid;
    const int c0 = lane, c1 = lane + 64;
    float v0, v1;
    if (r < N_LB) {
      v0 = (c0 < C_DIM) ? onehot[(size_t)r * C_DIM + c0] : 0.f;
      v1 = (c1 < C_DIM) ? onehot[(size_t)r * C_DIM + c1] : 0.f;
    } else {
      const float* lr = (r < 9216) ? (lg1 + (size_t)(r - 2048) * C_DIM)
                                   : (lg2 + (size_t)(r - 9216) * C_DIM);
      float x0 = (c0 < C_DIM) ? lr[c0] : -3e38f;
      float x1 = (c1 < C_DIM) ? lr[c1] : -3e38f;
      float m = fmaxf(x0, x1);
      #pragma unroll
      for (int o = 32; o; o >>= 1) m = fmaxf(m, __shfl_xor(m, o));
      float e0 = (c0 < C_DIM) ? EXP2F((x0 - m) * 1.44269504f) : 0.f;
      float e1 = (c1 < C_DIM) ? EXP2F((x1 - m) * 1.44269504f) : 0.f;
      float s = e0 + e1;
      #pragma unroll
      for (int o = 32; o; o >>= 1) s += __shfl_xor(s, o);
      float inv = 1.0f / s;
      v0 = e0 * inv;
      v1 = e1 * inv;
    }
    const int T = r >> 5, rr = r & 31;
    const int jj = (((rr >> 4) & 1) << 2) | (rr & 3);
    const int gg = (rr & 15) >> 2;
    {
      const int ch = c0 >> 4, qq = c0 & 15;
      v_ws[(size_t)T * 4096 + ch * 512 + gg * 128 + ((qq ^ (gg << 2)) << 3) + jj] = f2bf(v0);
    }
    {
      const int ch = c1 >> 4, qq = c1 & 15;
      v_ws[(size_t)T * 4096 + ch * 512 + gg * 128 + ((qq ^ (gg << 2)) << 3) + jj] = f2bf(v1);
    }
  } else {
    // passthrough copies
    const long long i4 = (long long)(bid - 8192) * 256 + tid;
    const long long f = i4 * 4;
    float4 v;
    if (f < 917504)        v = *(const float4*)(anc + f);
    else if (f < 1835008)  v = *(const float4*)(pos + (f - 917504));
    else if (f < 2097152)  v = *(const float4*)(lbf + (f - 1835008));
    else                   v = *(const float4*)(onehot + (f - 2097152));
    *(float4*)(out + f) = v;
  }
}

// ---------------- Kernel C: attention — i8 QK^T (K=64), K+V via LDS ----------------
__device__ __forceinline__ void stage_tiles(const signed char* kg, const short* vg,
                                            signed char* dk, short* dv, int wave, int lane) {
  #pragma unroll
  for (int i = 0; i < 2; ++i) {   // K tile: 8KB = 8 x 1KB chunks
    const int blk = wave * 2 + i;
    __builtin_amdgcn_global_load_lds(
        (const __attribute__((address_space(1))) void*)(kg + blk * 1024 + lane * 16),
        (__attribute__((address_space(3))) void*)(dk + blk * 1024), 16, 0, 0);
  }
  #pragma unroll
  for (int i = 0; i < 4; ++i) {   // V tile: 16KB = 16 x 1KB chunks
    const int blk = wave * 4 + i;
    __builtin_amdgcn_global_load_lds(
        (const __attribute__((address_space(1))) void*)(vg + blk * 512 + lane * 8),
        (__attribute__((address_space(3))) void*)(dv + blk * 512), 16, 0, 0);
  }
}

__global__ __launch_bounds__(256, 3) void k_attn(const signed char* __restrict__ ks8,
                                                 const short* __restrict__ vws,
                                                 short* __restrict__ pO,
                                                 float* __restrict__ pL,
                                                 float* __restrict__ outp,
                                                 int S, int nt2) {
  __shared__ __align__(16) signed char lk[2][8192];  // 16KB: two 64-row int8 K tiles
  __shared__ __align__(16) short       lv[2][8192];  // 32KB: two 64-row bf16 V tiles
  const int tid = threadIdx.x;
  const int wave = tid >> 6, lane = tid & 63;
  const int q = lane & 15, g = lane >> 4;
  const int bid = blockIdx.x;
  const int slice = bid % S;            // bid%8 == XCD: slice-local K/V stay in this XCD's L2
  const int qsup = (bid / S) * 4 + wave;
  const int t0h = slice * nt2;          // 64-row tile units

  // Q fragments (B operand of swapped QK^T): [set][kk], k-bytes kk*64 + g*16 (swizzled slot)
  i32x4 bQ[2][2];
  #pragma unroll
  for (int set = 0; set < 2; ++set)
    #pragma unroll
    for (int kk = 0; kk < 2; ++kk)
      bQ[set][kk] = *(const i32x4*)(ks8 + (size_t)(qsup * 32 + set * 16 + q) * 128 +
                                    sw3(kk * 4 + g, q) * 16);

  f32x4 zero = {0.f, 0.f, 0.f, 0.f};
  f32x4 oacc[2][7];
  #pragma unroll
  for (int set = 0; set < 2; ++set)
    #pragma unroll
    for (int c = 0; c < 7; ++c) oacc[set][c] = zero;
  float lsum[2] = {0.f, 0.f};

  int dsk[2];
  #pragma unroll
  for (int kk = 0; kk < 2; ++kk) dsk[kk] = q * 128 + sw3(kk * 4 + g, q) * 16;
  const int vfo = g * 128 + ((q ^ (g << 2)) << 3);

  stage_tiles(ks8 + (size_t)t0h * 8192, vws + (size_t)t0h * 8192, lk[0], lv[0], wave, lane);

  for (int t = 0; t < nt2; ++t) {
    const int cur = t & 1;
    // stage(t) was issued a full iteration ago -> this wait is covered
    asm volatile("s_waitcnt vmcnt(0)" ::: "memory");
    __builtin_amdgcn_s_barrier();
    __builtin_amdgcn_sched_barrier(0);
    if (t + 1 < nt2)
      stage_tiles(ks8 + (size_t)(t0h + t + 1) * 8192, vws + (size_t)(t0h + t + 1) * 8192,
                  lk[cur ^ 1], lv[cur ^ 1], wave, lane);

    const signed char* lkc = lk[cur];
    const short* lvc = lv[cur];
    #pragma unroll
    for (int sub = 0; sub < 2; ++sub) {
      // K fragments: rows [sub*32, sub*32+32) as two 16-row groups
      i32x4 aK0[2], aK1[2];
      #pragma unroll
      for (int kk = 0; kk < 2; ++kk) {
        aK0[kk] = *(const i32x4*)(lkc + (sub * 32 + 0)  * 128 + dsk[kk]);
        aK1[kk] = *(const i32x4*)(lkc + (sub * 32 + 16) * 128 + dsk[kk]);
      }
      // swapped QK^T: i8, K=64 x2 -> exact i32 scores
      i32x4 iz = {0, 0, 0, 0};
      i32x4 s0[2] = {iz, iz}, s1[2] = {iz, iz};
      __builtin_amdgcn_s_setprio(1);
      #pragma unroll
      for (int kk = 0; kk < 2; ++kk)
        #pragma unroll
        for (int set = 0; set < 2; ++set) {
          s0[set] = __builtin_amdgcn_mfma_i32_16x16x64_i8(aK0[kk], bQ[set][kk], s0[set], 0, 0, 0);
          s1[set] = __builtin_amdgcn_mfma_i32_16x16x64_i8(aK1[kk], bQ[set][kk], s1[set], 0, 0, 0);
        }
      __builtin_amdgcn_s_setprio(0);

      // V fragments from LDS
      s16x8 bV[7];
      #pragma unroll
      for (int c = 0; c < 7; ++c) bV[c] = *(const s16x8*)(lvc + sub * 4096 + c * 512 + vfo);

      // p = exp2(acc * SCONV), unnormalized (max score ~14.43; cancels in O/l)
      s16x8 pf[2];
      #pragma unroll
      for (int set = 0; set < 2; ++set) {
        float p[8];
        #pragma unroll
        for (int r = 0; r < 4; ++r) {
          p[r]     = EXP2F((float)s0[set][r] * SCONV);
          p[r + 4] = EXP2F((float)s1[set][r] * SCONV);
        }
        lsum[set] += ((p[0] + p[1]) + (p[2] + p[3])) + ((p[4] + p[5]) + (p[6] + p[7]));
        union { unsigned w[4]; s16x8 h; } pu;
        pu.w[0] = cvtpk_bf16(p[0], p[1]);
        pu.w[1] = cvtpk_bf16(p[2], p[3]);
        pu.w[2] = cvtpk_bf16(p[4], p[5]);
        pu.w[3] = cvtpk_bf16(p[6], p[7]);
        pf[set] = pu.h;
      }

      // PV (bf16, V pre-permuted to match P fragment order)
      __builtin_amdgcn_s_setprio(1);
      #pragma unroll
      for (int c = 0; c < 7; ++c)
        #pragma unroll
        for (int set = 0; set < 2; ++set)
          oacc[set][c] = __builtin_amdgcn_mfma_f32_16x16x32_bf16(pf[set], bV[c], oacc[set][c], 0, 0, 0);
      __builtin_amdgcn_s_setprio(0);
    }
  }

  // epilogue
  #pragma unroll
  for (int set = 0; set < 2; ++set) {
    float ls = lsum[set];
    ls += __shfl_xor(ls, 16);
    ls += __shfl_xor(ls, 32);
    const int row0 = qsup * 32 + set * 16;
    if (S == 1) {
      float linv[4];
      #pragma unroll
      for (int r = 0; r < 4; ++r) linv[r] = 1.0f / __shfl(ls, (g << 2) | r);
      #pragma unroll
      for (int c = 0; c < 7; ++c) {
        const int col = c * 16 + q;
        if (col < C_DIM)
          #pragma unroll
          for (int r = 0; r < 4; ++r)
            outp[(size_t)(row0 + (g << 2) + r) * C_DIM + col] = oacc[set][c][r] * linv[r];
      }
    } else {
      if (lane < 16) pL[(size_t)slice * N_TOT + row0 + lane] = ls;
      #pragma unroll
      for (int c = 0; c < 7; ++c)
        #pragma unroll
        for (int r = 0; r < 4; ++r)
          pO[((size_t)slice * N_TOT + row0 + (g << 2) + r) * 112 + c * 16 + q] =
              f2bf(oacc[set][c][r]);
    }
  }
}

// ---------------- Kernel D: combine K-split partials ----------------
__global__ void k_combine(const short* __restrict__ pO, const float* __restrict__ pL,
                          float* __restrict__ out, int S) {
  const int row = blockIdx.x * 2 + (threadIdx.x >> 7);
  const int c = threadIdx.x & 127;
  float l = 0.f, o = 0.f;
  for (int s = 0; s < S; ++s) {
    l += pL[(size_t)s * N_TOT + row];
    if (c < 112) o += bf2f(pO[((size_t)s * N_TOT + row) * 112 + c]);
  }
  if (c < C_DIM) out[(size_t)row * C_DIM + c] = o / l;
}

extern "C" void kernel_launch(void* const* d_in, const int* in_sizes, int n_in,
                              void* d_out, int out_size, void* d_ws, size_t ws_size,
                              hipStream_t stream) {
  const float* anchor   = (const float*)d_in[0];  // 7168x128
  const float* positive = (const float*)d_in[1];  // 7168x128
  const float* lb_feat  = (const float*)d_in[2];  // 2048x128
  const float* lb_onehot= (const float*)d_in[3];  // 2048x100
  const float* lg1      = (const float*)d_in[5];  // 7168x100
  const float* lg2      = (const float*)d_in[6];  // 7168x100
  float* out = (float*)d_out;

  signed char* ks8 = (signed char*)d_ws;         // 2 MB (int8 feats, Q and K shared)
  short* v_ws      = (short*)(ks8 + 2097152);    // 4 MB (bf16, PV B-frag order)
  float* pL        = (float*)(v_ws + 2097152);   // 512 KB (8 slices max)
  short* pO        = (short*)(pL + 8 * N_TOT);   // S * 16384 * 112 * 2B

  int S = 8;
  while (S > 1 && 6815744ull + (size_t)S * N_TOT * 112 * 2 > ws_size) S >>= 1;
  const int nt2 = (512 / S) >> 1;

  k_prep<<<10440, 256, 0, stream>>>(anchor, positive, lb_feat, lb_onehot, lg1, lg2,
                                    ks8, v_ws, out);

  float* attn_out = out + 2301952;
  k_attn<<<128 * S, 256, 0, stream>>>(ks8, v_ws, pO, pL, attn_out, S, nt2);
  if (S > 1)
    k_combine<<<N_TOT / 2, 256, 0, stream>>>(pO, pL, attn_out, S);
}

// Round 8
// 125.803 us; speedup vs baseline: 1.4165x; 1.0216x over previous
//
#include <hip/hip_runtime.h>
#include <hip/hip_bf16.h>
#include <stdint.h>

#define N_TOT   16384
#define N_LB    2048
#define C_DIM   100

typedef __attribute__((ext_vector_type(8))) short s16x8;
typedef __attribute__((ext_vector_type(4))) float f32x4;
typedef __attribute__((ext_vector_type(4))) int   i32x4;

#if __has_builtin(__builtin_amdgcn_exp2f)
#define EXP2F __builtin_amdgcn_exp2f
#else
#define EXP2F exp2f
#endif

// score scale: 10*log2(e) / 127^2  (int8 dot -> log2-domain score)
#define SCONV 8.94477e-4f

__device__ __forceinline__ short f2bf(float x) {
  union { float f; unsigned u; } v; v.f = x;
  unsigned r = (v.u + 0x7fffu + ((v.u >> 16) & 1u)) >> 16;
  return (short)r;
}
__device__ __forceinline__ float bf2f(short h) {
  union { unsigned u; float f; } v; v.u = ((unsigned)(unsigned short)h) << 16; return v.f;
}
__device__ __forceinline__ unsigned cvtpk_bf16(float a, float b) {
  unsigned r;
  asm("v_cvt_pk_bf16_f32 %0, %1, %2" : "=v"(r) : "v"(a), "v"(b));
  return r;
}
// 16-byte-slot swizzle within a 128B row: slot' = (s ^ q ^ (q>>3)) & 7
// -> the 16 lanes of a row-group hit 8 slots 2x each = 2-way (free) on LDS banks
__device__ __forceinline__ int sw3(int s, int q) {
  return (s ^ q ^ (q >> 3)) & 7;
}

// ---------------- Kernel P: fused prep (normalize->int8 + classval + copies) ----------------
__global__ __launch_bounds__(256) void k_prep(const float* __restrict__ anc,
                                              const float* __restrict__ pos,
                                              const float* __restrict__ lbf,
                                              const float* __restrict__ onehot,
                                              const float* __restrict__ lg1,
                                              const float* __restrict__ lg2,
                                              signed char* __restrict__ ks8,
                                              short* __restrict__ v_ws,
                                              float* __restrict__ out) {
  const int bid = blockIdx.x, tid = threadIdx.x;
  const int wid = tid >> 6, lane = tid & 63;
  if (bid < 4096) {
    // l2-normalize -> int8 (x127), byte-slot-swizzled row-major [16384][128]
    const int r = bid * 4 + wid;
    const float* src = (r < N_LB) ? (lbf + (size_t)r * 128)
                     : ((r < 9216) ? (anc + (size_t)(r - 2048) * 128)
                                   : (pos + (size_t)(r - 9216) * 128));
    float2 x = *(const float2*)(src + lane * 2);
    float ss = x.x * x.x + x.y * x.y;
    #pragma unroll
    for (int o = 32; o; o >>= 1) ss += __shfl_xor(ss, o);
    float s127 = rsqrtf(fmaxf(ss, 1e-24f)) * 127.0f;
    int a = __float2int_rn(x.x * s127);
    int b = __float2int_rn(x.y * s127);
    a = max(-127, min(127, a));
    b = max(-127, min(127, b));
    const int q = r & 15;
    const int slot = sw3(lane >> 3, q);
    *(unsigned short*)(ks8 + (size_t)r * 128 + slot * 16 + ((lane * 2) & 15)) =
        (unsigned short)((a & 0xff) | ((b & 0xff) << 8));
  } else if (bid < 8192) {
    // class_val rows -> bf16, PV B-frag order (unchanged, verified R1-R5)
    const int r = (bid - 4096) * 4 + wid;
    const int c0 = lane, c1 = lane + 64;
    float v0, v1;
    if (r < N_LB) {
      v0 = (c0 < C_DIM) ? onehot[(size_t)r * C_DIM + c0] : 0.f;
      v1 = (c1 < C_DIM) ? onehot[(size_t)r * C_DIM + c1] : 0.f;
    } else {
      const float* lr = (r < 9216) ? (lg1 + (size_t)(r - 2048) * C_DIM)
                                   : (lg2 + (size_t)(r - 9216) * C_DIM);
      float x0 = (c0 < C_DIM) ? lr[c0] : -3e38f;
      float x1 = (c1 < C_DIM) ? lr[c1] : -3e38f;
      float m = fmaxf(x0, x1);
      #pragma unroll
      for (int o = 32; o; o >>= 1) m = fmaxf(m, __shfl_xor(m, o));
      float e0 = (c0 < C_DIM) ? EXP2F((x0 - m) * 1.44269504f) : 0.f;
      float e1 = (c1 < C_DIM) ? EXP2F((x1 - m) * 1.44269504f) : 0.f;
      float s = e0 + e1;
      #pragma unroll
      for (int o = 32; o; o >>= 1) s += __shfl_xor(s, o);
      float inv = 1.0f / s;
      v0 = e0 * inv;
      v1 = e1 * inv;
    }
    const int T = r >> 5, rr = r & 31;
    const int jj = (((rr >> 4) & 1) << 2) | (rr & 3);
    const int gg = (rr & 15) >> 2;
    {
      const int ch = c0 >> 4, qq = c0 & 15;
      v_ws[(size_t)T * 4096 + ch * 512 + gg * 128 + ((qq ^ (gg << 2)) << 3) + jj] = f2bf(v0);
    }
    {
      const int ch = c1 >> 4, qq = c1 & 15;
      v_ws[(size_t)T * 4096 + ch * 512 + gg * 128 + ((qq ^ (gg << 2)) << 3) + jj] = f2bf(v1);
    }
  } else {
    // passthrough copies
    const long long i4 = (long long)(bid - 8192) * 256 + tid;
    const long long f = i4 * 4;
    float4 v;
    if (f < 917504)        v = *(const float4*)(anc + f);
    else if (f < 1835008)  v = *(const float4*)(pos + (f - 917504));
    else if (f < 2097152)  v = *(const float4*)(lbf + (f - 1835008));
    else                   v = *(const float4*)(onehot + (f - 2097152));
    *(float4*)(out + f) = v;
  }
}

// ---------------- Kernel C: attention — i8 QK^T (K=64), K+V via LDS ----------------
__device__ __forceinline__ void stage_tiles(const signed char* kg, const short* vg,
                                            signed char* dk, short* dv, int wave, int lane) {
  #pragma unroll
  for (int i = 0; i < 2; ++i) {   // K tile: 8KB = 8 x 1KB chunks
    const int blk = wave * 2 + i;
    __builtin_amdgcn_global_load_lds(
        (const __attribute__((address_space(1))) void*)(kg + blk * 1024 + lane * 16),
        (__attribute__((address_space(3))) void*)(dk + blk * 1024), 16, 0, 0);
  }
  #pragma unroll
  for (int i = 0; i < 4; ++i) {   // V tile: 16KB = 16 x 1KB chunks
    const int blk = wave * 4 + i;
    __builtin_amdgcn_global_load_lds(
        (const __attribute__((address_space(1))) void*)(vg + blk * 512 + lane * 8),
        (__attribute__((address_space(3))) void*)(dv + blk * 512), 16, 0, 0);
  }
}

__global__ __launch_bounds__(256, 3) void k_attn(const signed char* __restrict__ ks8,
                                                 const short* __restrict__ vws,
                                                 short* __restrict__ pO,
                                                 float* __restrict__ pL,
                                                 float* __restrict__ outp,
                                                 int S, int nt2) {
  __shared__ __align__(16) signed char lk[2][8192];  // 16KB: two 64-row int8 K tiles
  __shared__ __align__(16) short       lv[2][8192];  // 32KB: two 64-row bf16 V tiles
  const int tid = threadIdx.x;
  const int wave = tid >> 6, lane = tid & 63;
  const int q = lane & 15, g = lane >> 4;
  const int bid = blockIdx.x;
  const int slice = bid % S;            // bid%8 == XCD: slice-local K/V stay in this XCD's L2
  const int qsup = (bid / S) * 4 + wave;
  const int t0h = slice * nt2;          // 64-row tile units

  // Q fragments (B operand of swapped QK^T): [set][kk], k-bytes kk*64 + g*16 (swizzled slot)
  i32x4 bQ[2][2];
  #pragma unroll
  for (int set = 0; set < 2; ++set)
    #pragma unroll
    for (int kk = 0; kk < 2; ++kk)
      bQ[set][kk] = *(const i32x4*)(ks8 + (size_t)(qsup * 32 + set * 16 + q) * 128 +
                                    sw3(kk * 4 + g, q) * 16);

  f32x4 zero = {0.f, 0.f, 0.f, 0.f};
  f32x4 oacc[2][7];
  #pragma unroll
  for (int set = 0; set < 2; ++set)
    #pragma unroll
    for (int c = 0; c < 7; ++c) oacc[set][c] = zero;
  float lsum[2] = {0.f, 0.f};

  int dsk[2];
  #pragma unroll
  for (int kk = 0; kk < 2; ++kk) dsk[kk] = q * 128 + sw3(kk * 4 + g, q) * 16;
  const int vfo = g * 128 + ((q ^ (g << 2)) << 3);

  stage_tiles(ks8 + (size_t)t0h * 8192, vws + (size_t)t0h * 8192, lk[0], lv[0], wave, lane);

  for (int t = 0; t < nt2; ++t) {
    const int cur = t & 1;
    // stage(t) was issued a full iteration ago -> this wait is covered
    asm volatile("s_waitcnt vmcnt(0)" ::: "memory");
    __builtin_amdgcn_s_barrier();
    __builtin_amdgcn_sched_barrier(0);
    if (t + 1 < nt2)
      stage_tiles(ks8 + (size_t)(t0h + t + 1) * 8192, vws + (size_t)(t0h + t + 1) * 8192,
                  lk[cur ^ 1], lv[cur ^ 1], wave, lane);

    const signed char* lkc = lk[cur];
    const short* lvc = lv[cur];
    #pragma unroll
    for (int sub = 0; sub < 2; ++sub) {
      // K fragments: rows [sub*32, sub*32+32) as two 16-row groups
      i32x4 aK0[2], aK1[2];
      #pragma unroll
      for (int kk = 0; kk < 2; ++kk) {
        aK0[kk] = *(const i32x4*)(lkc + (sub * 32 + 0)  * 128 + dsk[kk]);
        aK1[kk] = *(const i32x4*)(lkc + (sub * 32 + 16) * 128 + dsk[kk]);
      }
      // swapped QK^T: i8, K=64 x2 -> exact i32 scores
      i32x4 iz = {0, 0, 0, 0};
      i32x4 s0[2] = {iz, iz}, s1[2] = {iz, iz};
      __builtin_amdgcn_s_setprio(1);
      #pragma unroll
      for (int kk = 0; kk < 2; ++kk)
        #pragma unroll
        for (int set = 0; set < 2; ++set) {
          s0[set] = __builtin_amdgcn_mfma_i32_16x16x64_i8(aK0[kk], bQ[set][kk], s0[set], 0, 0, 0);
          s1[set] = __builtin_amdgcn_mfma_i32_16x16x64_i8(aK1[kk], bQ[set][kk], s1[set], 0, 0, 0);
        }
      __builtin_amdgcn_s_setprio(0);

      // V fragments from LDS
      s16x8 bV[7];
      #pragma unroll
      for (int c = 0; c < 7; ++c) bV[c] = *(const s16x8*)(lvc + sub * 4096 + c * 512 + vfo);

      // p = exp2(acc * SCONV), unnormalized (max score ~14.43; cancels in O/l)
      s16x8 pf[2];
      #pragma unroll
      for (int set = 0; set < 2; ++set) {
        float p[8];
        #pragma unroll
        for (int r = 0; r < 4; ++r) {
          p[r]     = EXP2F((float)s0[set][r] * SCONV);
          p[r + 4] = EXP2F((float)s1[set][r] * SCONV);
        }
        lsum[set] += ((p[0] + p[1]) + (p[2] + p[3])) + ((p[4] + p[5]) + (p[6] + p[7]));
        union { unsigned w[4]; s16x8 h; } pu;
        pu.w[0] = cvtpk_bf16(p[0], p[1]);
        pu.w[1] = cvtpk_bf16(p[2], p[3]);
        pu.w[2] = cvtpk_bf16(p[4], p[5]);
        pu.w[3] = cvtpk_bf16(p[6], p[7]);
        pf[set] = pu.h;
      }

      // PV (bf16, V pre-permuted to match P fragment order)
      __builtin_amdgcn_s_setprio(1);
      #pragma unroll
      for (int c = 0; c < 7; ++c)
        #pragma unroll
        for (int set = 0; set < 2; ++set)
          oacc[set][c] = __builtin_amdgcn_mfma_f32_16x16x32_bf16(pf[set], bV[c], oacc[set][c], 0, 0, 0);
      __builtin_amdgcn_s_setprio(0);
    }
  }

  // epilogue
  #pragma unroll
  for (int set = 0; set < 2; ++set) {
    float ls = lsum[set];
    ls += __shfl_xor(ls, 16);
    ls += __shfl_xor(ls, 32);
    const int row0 = qsup * 32 + set * 16;
    if (S == 1) {
      float linv[4];
      #pragma unroll
      for (int r = 0; r < 4; ++r) linv[r] = 1.0f / __shfl(ls, (g << 2) | r);
      #pragma unroll
      for (int c = 0; c < 7; ++c) {
        const int col = c * 16 + q;
        if (col < C_DIM)
          #pragma unroll
          for (int r = 0; r < 4; ++r)
            outp[(size_t)(row0 + (g << 2) + r) * C_DIM + col] = oacc[set][c][r] * linv[r];
      }
    } else {
      if (lane < 16) pL[(size_t)slice * N_TOT + row0 + lane] = ls;
      #pragma unroll
      for (int c = 0; c < 7; ++c)
        #pragma unroll
        for (int r = 0; r < 4; ++r)
          pO[((size_t)slice * N_TOT + row0 + (g << 2) + r) * 112 + c * 16 + q] =
              f2bf(oacc[set][c][r]);
    }
  }
}

// ---------------- Kernel D: combine K-split partials ----------------
__global__ void k_combine(const short* __restrict__ pO, const float* __restrict__ pL,
                          float* __restrict__ out, int S) {
  const int row = blockIdx.x * 2 + (threadIdx.x >> 7);
  const int c = threadIdx.x & 127;
  float l = 0.f, o = 0.f;
  for (int s = 0; s < S; ++s) {
    l += pL[(size_t)s * N_TOT + row];
    if (c < 112) o += bf2f(pO[((size_t)s * N_TOT + row) * 112 + c]);
  }
  if (c < C_DIM) out[(size_t)row * C_DIM + c] = o / l;
}

extern "C" void kernel_launch(void* const* d_in, const int* in_sizes, int n_in,
                              void* d_out, int out_size, void* d_ws, size_t ws_size,
                              hipStream_t stream) {
  const float* anchor   = (const float*)d_in[0];  // 7168x128
  const float* positive = (const float*)d_in[1];  // 7168x128
  const float* lb_feat  = (const float*)d_in[2];  // 2048x128
  const float* lb_onehot= (const float*)d_in[3];  // 2048x100
  const float* lg1      = (const float*)d_in[5];  // 7168x100
  const float* lg2      = (const float*)d_in[6];  // 7168x100
  float* out = (float*)d_out;

  signed char* ks8 = (signed char*)d_ws;         // 2 MB (int8 feats, Q and K shared)
  short* v_ws      = (short*)(ks8 + 2097152);    // 4 MB (bf16, PV B-frag order)
  float* pL        = (float*)(v_ws + 2097152);   // 512 KB (8 slices max)
  short* pO        = (short*)(pL + 8 * N_TOT);   // S * 16384 * 112 * 2B

  int S = 8;
  while (S > 1 && 6815744ull + (size_t)S * N_TOT * 112 * 2 > ws_size) S >>= 1;
  const int nt2 = (512 / S) >> 1;

  k_prep<<<10440, 256, 0, stream>>>(anchor, positive, lb_feat, lb_onehot, lg1, lg2,
                                    ks8, v_ws, out);

  float* attn_out = out + 2301952;
  k_attn<<<128 * S, 256, 0, stream>>>(ks8, v_ws, pO, pL, attn_out, S, nt2);
  if (S > 1)
    k_combine<<<N_TOT / 2, 256, 0, stream>>>(pO, pL, attn_out, S);
}